// Round 1
// baseline (1133.958 us; speedup 1.0000x reference)
//
#include <hip/hip_runtime.h>
#include <hip/hip_bf16.h>
#include <math.h>

// Problem dims (fixed by reference)
#define T_TOK 8192          // B*S tokens
#define DIM   2048          // D
#define NE    8             // experts
#define MDIM  1024          // intermediate
#define TK    16384         // T*K token copies
#define CAP   (TK + 128)    // slack rows so edge tiles can over-read safely

typedef __attribute__((ext_vector_type(8))) short bf16x8;
typedef __attribute__((ext_vector_type(4))) float f32x4;

typedef __attribute__((address_space(3))) unsigned char* lds_ptr_t;
typedef const __attribute__((address_space(1))) unsigned char* glb_ptr_t;

__device__ __forceinline__ unsigned short f2bf(float f) {
  union { float f; unsigned u; } v; v.f = f;
  unsigned r = v.u + 0x7fffu + ((v.u >> 16) & 1u);  // round-to-nearest-even
  return (unsigned short)(r >> 16);
}

__device__ __forceinline__ void gload_lds16(const void* g, void* l) {
  // each lane loads 16B from its own global addr; lands at lds_base + lane*16
  __builtin_amdgcn_global_load_lds((glb_ptr_t)g, (lds_ptr_t)l, 16, 0, 0);
}

// ---------------- router: fp64 logits, top-2, softmax weights ----------------
__global__ __launch_bounds__(256) void router_kernel(
    const float* __restrict__ x, const float* __restrict__ wg,
    int* __restrict__ counts, int* __restrict__ tok_eid, float* __restrict__ tok_w) {
  int gwave = (blockIdx.x * 256 + threadIdx.x) >> 6;
  int lane = threadIdx.x & 63;
  if (gwave >= T_TOK) return;
  const float* xr = x + (size_t)gwave * DIM;
  double acc[NE];
#pragma unroll
  for (int e = 0; e < NE; e++) acc[e] = 0.0;
  for (int d = lane; d < DIM; d += 64) {
    double xv = (double)xr[d];
    const float* wr = wg + (size_t)d * NE;
#pragma unroll
    for (int e = 0; e < NE; e++) acc[e] += xv * (double)wr[e];
  }
#pragma unroll
  for (int e = 0; e < NE; e++) {
    double v = acc[e];
#pragma unroll
    for (int off = 32; off > 0; off >>= 1) v += __shfl_down(v, off, 64);
    acc[e] = v;
  }
  if (lane == 0) {
    int b0 = 0; double l0 = acc[0];
#pragma unroll
    for (int e = 1; e < NE; e++) { if (acc[e] > l0) { l0 = acc[e]; b0 = e; } }
    int b1 = -1; double l1 = -1.0e300;
#pragma unroll
    for (int e = 0; e < NE; e++) { if (e != b0 && acc[e] > l1) { l1 = acc[e]; b1 = e; } }
    double w0 = 1.0 / (1.0 + exp(l1 - l0));
    tok_eid[2 * gwave]     = b0;
    tok_eid[2 * gwave + 1] = b1;
    tok_w[2 * gwave]     = (float)w0;
    tok_w[2 * gwave + 1] = (float)(1.0 - w0);
    atomicAdd(&counts[b0], 1);
    atomicAdd(&counts[b1], 1);
  }
}

__global__ void scan_kernel(const int* __restrict__ counts, int* __restrict__ offsets) {
  if (threadIdx.x == 0) {
    int s = 0;
    for (int e = 0; e < NE; e++) { offsets[e] = s; s += counts[e]; }
    offsets[NE] = s;
  }
}

// ---------------- dispatch: slot assignment + gather x -> sorted_x (bf16) ----
__global__ __launch_bounds__(256) void dispatch_kernel(
    const float* __restrict__ x, const int* __restrict__ tok_eid,
    const float* __restrict__ tok_w, const int* __restrict__ offsets,
    int* __restrict__ fill, int* __restrict__ row_token,
    float* __restrict__ row_weight, unsigned short* __restrict__ sorted_x) {
  int t = blockIdx.x;
  __shared__ int slots[2];
  if (threadIdx.x < 2) {
    int e = tok_eid[2 * t + threadIdx.x];
    int pos = atomicAdd(&fill[e], 1);
    int slot = offsets[e] + pos;
    slots[threadIdx.x] = slot;
    row_token[slot] = t;
    row_weight[slot] = tok_w[2 * t + threadIdx.x];
  }
  __syncthreads();
  size_t s0 = (size_t)slots[0] * DIM, s1 = (size_t)slots[1] * DIM;
  const float4* xr = (const float4*)(x + (size_t)t * DIM);
#pragma unroll
  for (int i = threadIdx.x; i < DIM / 4; i += 256) {
    float4 v = xr[i];
    ushort4 b;
    b.x = f2bf(v.x); b.y = f2bf(v.y); b.z = f2bf(v.z); b.w = f2bf(v.w);
    *(ushort4*)(sorted_x + s0 + (size_t)i * 4) = b;
    *(ushort4*)(sorted_x + s1 + (size_t)i * 4) = b;
  }
}

// ---------------- weight cast + transpose: f32 [R][C] -> bf16 [C][R] --------
__global__ __launch_bounds__(256) void transpose_cast_kernel(
    const float* __restrict__ in, unsigned short* __restrict__ out, int R, int C) {
  __shared__ unsigned short tile[32][33];
  int e = blockIdx.z;
  const float* inp = in + (size_t)e * R * C;
  unsigned short* outp = out + (size_t)e * R * C;
  int c0 = blockIdx.x * 32, r0 = blockIdx.y * 32;
  int tx = threadIdx.x & 31, ty = threadIdx.x >> 5;  // ty 0..7
#pragma unroll
  for (int i = 0; i < 32; i += 8)
    tile[ty + i][tx] = f2bf(inp[(size_t)(r0 + ty + i) * C + (c0 + tx)]);
  __syncthreads();
#pragma unroll
  for (int i = 0; i < 32; i += 8)
    outp[(size_t)(c0 + ty + i) * R + (r0 + tx)] = tile[tx][ty + i];
}

// ---------------- GEMM12: inter = silu(A@wi0) * (A@wi1), bf16 MFMA ----------
// A: sorted_x [CAP][DIM] bf16 row-major; W0t/W1t: [NE][MDIM][DIM] bf16 (N-major, K-contig)
__global__ __launch_bounds__(256) void gemm12_kernel(
    const unsigned short* __restrict__ A, const unsigned short* __restrict__ W0t,
    const unsigned short* __restrict__ W1t, const int* __restrict__ offsets,
    unsigned short* __restrict__ inter) {
  int e = blockIdx.z;
  int row0 = offsets[e], row_end = offsets[e + 1];
  int tile_r0 = row0 + blockIdx.x * 128;
  if (tile_r0 >= row_end) return;
  int col0 = blockIdx.y * 64;

  __shared__ unsigned short As[128 * 32];
  __shared__ unsigned short B0s[64 * 32];
  __shared__ unsigned short B1s[64 * 32];

  int tid = threadIdx.x;
  int wave = tid >> 6, lane = tid & 63;
  int wm = wave >> 1, wn = wave & 1;  // wave tile: 64 rows x 32 cols

  const unsigned short* B0 = W0t + ((size_t)e * MDIM + col0) * DIM;
  const unsigned short* B1 = W1t + ((size_t)e * MDIM + col0) * DIM;

  f32x4 acc0[4][2], acc1[4][2];
#pragma unroll
  for (int i = 0; i < 4; i++)
#pragma unroll
    for (int j = 0; j < 2; j++) {
      acc0[i][j] = (f32x4){0.f, 0.f, 0.f, 0.f};
      acc1[i][j] = (f32x4){0.f, 0.f, 0.f, 0.f};
    }

  int lrow = lane >> 2;            // 0..15
  int lkoff = (lane & 3) * 8;      // element offset within 32-wide K chunk

  for (int k0 = 0; k0 < DIM; k0 += 32) {
    // stage A: wave w covers rows [w*32, w*32+32), 2 calls of 16 rows
#pragma unroll
    for (int c = 0; c < 2; c++) {
      int r = wave * 32 + c * 16 + lrow;
      gload_lds16(A + (size_t)(tile_r0 + r) * DIM + k0 + lkoff,
                  &As[(wave * 32 + c * 16) * 32]);
    }
    // stage B0/B1: wave w covers rows [w*16, w*16+16), 1 call each
    {
      int r = wave * 16 + lrow;
      gload_lds16(B0 + (size_t)r * DIM + k0 + lkoff, &B0s[(wave * 16) * 32]);
      gload_lds16(B1 + (size_t)r * DIM + k0 + lkoff, &B1s[(wave * 16) * 32]);
    }
    __syncthreads();
    bf16x8 af[4], b0f[2], b1f[2];
#pragma unroll
    for (int mi = 0; mi < 4; mi++)
      af[mi] = *(const bf16x8*)&As[(wm * 64 + mi * 16 + (lane & 15)) * 32 + (lane >> 4) * 8];
#pragma unroll
    for (int ni = 0; ni < 2; ni++) {
      b0f[ni] = *(const bf16x8*)&B0s[(wn * 32 + ni * 16 + (lane & 15)) * 32 + (lane >> 4) * 8];
      b1f[ni] = *(const bf16x8*)&B1s[(wn * 32 + ni * 16 + (lane & 15)) * 32 + (lane >> 4) * 8];
    }
#pragma unroll
    for (int mi = 0; mi < 4; mi++)
#pragma unroll
      for (int ni = 0; ni < 2; ni++) {
        acc0[mi][ni] = __builtin_amdgcn_mfma_f32_16x16x32_bf16(af[mi], b0f[ni], acc0[mi][ni], 0, 0, 0);
        acc1[mi][ni] = __builtin_amdgcn_mfma_f32_16x16x32_bf16(af[mi], b1f[ni], acc1[mi][ni], 0, 0, 0);
      }
    __syncthreads();
  }
  // epilogue: silu(h0)*h1 -> inter (bf16). C/D: col=lane&15, row=(lane>>4)*4+reg
#pragma unroll
  for (int mi = 0; mi < 4; mi++)
#pragma unroll
    for (int reg = 0; reg < 4; reg++) {
      int grow = tile_r0 + wm * 64 + mi * 16 + (lane >> 4) * 4 + reg;
      if (grow < row_end) {
#pragma unroll
        for (int ni = 0; ni < 2; ni++) {
          float h0 = acc0[mi][ni][reg];
          float h1 = acc1[mi][ni][reg];
          float g = h0 / (1.0f + __expf(-h0));
          int col = col0 + wn * 32 + ni * 16 + (lane & 15);
          inter[(size_t)grow * MDIM + col] = f2bf(g * h1);
        }
      }
    }
}

// ---------------- GEMM3: out[t] += w * (inter @ wo), scatter-atomic ---------
// A: inter [CAP][MDIM] bf16; Wot: [NE][DIM][MDIM] bf16 (N-major, K-contig)
__global__ __launch_bounds__(256) void gemm3_kernel(
    const unsigned short* __restrict__ A, const unsigned short* __restrict__ Wot,
    const int* __restrict__ offsets, const int* __restrict__ row_token,
    const float* __restrict__ row_weight, float* __restrict__ out) {
  int e = blockIdx.z;
  int row0 = offsets[e], row_end = offsets[e + 1];
  int tile_r0 = row0 + blockIdx.x * 128;
  if (tile_r0 >= row_end) return;
  int col0 = blockIdx.y * 128;

  __shared__ unsigned short As[128 * 32];
  __shared__ unsigned short Bs[128 * 32];

  int tid = threadIdx.x;
  int wave = tid >> 6, lane = tid & 63;
  int wm = wave >> 1, wn = wave & 1;  // wave tile: 64 x 64

  const unsigned short* B = Wot + ((size_t)e * DIM + col0) * MDIM;

  f32x4 acc[4][4];
#pragma unroll
  for (int i = 0; i < 4; i++)
#pragma unroll
    for (int j = 0; j < 4; j++) acc[i][j] = (f32x4){0.f, 0.f, 0.f, 0.f};

  int lrow = lane >> 2;
  int lkoff = (lane & 3) * 8;

  for (int k0 = 0; k0 < MDIM; k0 += 32) {
#pragma unroll
    for (int c = 0; c < 2; c++) {
      int r = wave * 32 + c * 16 + lrow;
      gload_lds16(A + (size_t)(tile_r0 + r) * MDIM + k0 + lkoff,
                  &As[(wave * 32 + c * 16) * 32]);
      gload_lds16(B + (size_t)r * MDIM + k0 + lkoff,
                  &Bs[(wave * 32 + c * 16) * 32]);
    }
    __syncthreads();
    bf16x8 af[4], bfr[4];
#pragma unroll
    for (int mi = 0; mi < 4; mi++)
      af[mi] = *(const bf16x8*)&As[(wm * 64 + mi * 16 + (lane & 15)) * 32 + (lane >> 4) * 8];
#pragma unroll
    for (int ni = 0; ni < 4; ni++)
      bfr[ni] = *(const bf16x8*)&Bs[(wn * 64 + ni * 16 + (lane & 15)) * 32 + (lane >> 4) * 8];
#pragma unroll
    for (int mi = 0; mi < 4; mi++)
#pragma unroll
      for (int ni = 0; ni < 4; ni++)
        acc[mi][ni] = __builtin_amdgcn_mfma_f32_16x16x32_bf16(af[mi], bfr[ni], acc[mi][ni], 0, 0, 0);
    __syncthreads();
  }
  // epilogue: weighted scatter-add into out
#pragma unroll
  for (int mi = 0; mi < 4; mi++)
#pragma unroll
    for (int reg = 0; reg < 4; reg++) {
      int grow = tile_r0 + wm * 64 + mi * 16 + (lane >> 4) * 4 + reg;
      if (grow < row_end) {
        int t = row_token[grow];
        float w = row_weight[grow];
        float* orow = out + (size_t)t * DIM + col0 + wn * 64 + (lane & 15);
#pragma unroll
        for (int ni = 0; ni < 4; ni++)
          atomicAdd(orow + ni * 16, w * acc[mi][ni][reg]);
      }
    }
}

// ---------------------------------------------------------------------------
extern "C" void kernel_launch(void* const* d_in, const int* in_sizes, int n_in,
                              void* d_out, int out_size, void* d_ws, size_t ws_size,
                              hipStream_t stream) {
  const float* x   = (const float*)d_in[0];
  const float* wg  = (const float*)d_in[1];
  const float* wi0 = (const float*)d_in[2];
  const float* wi1 = (const float*)d_in[3];
  const float* wo  = (const float*)d_in[4];
  float* out = (float*)d_out;

  char* ws = (char*)d_ws;
  size_t off = 0;
  auto alloc = [&](size_t bytes) -> void* {
    void* p = ws + off;
    off = (off + bytes + 255) & ~(size_t)255;
    return p;
  };
  int*   counts     = (int*)alloc(NE * 4);
  int*   fill       = (int*)alloc(NE * 4);
  int*   offsets    = (int*)alloc((NE + 1) * 4);
  int*   tok_eid    = (int*)alloc((size_t)2 * T_TOK * 4);
  float* tok_w      = (float*)alloc((size_t)2 * T_TOK * 4);
  int*   row_token  = (int*)alloc((size_t)CAP * 4);
  float* row_weight = (float*)alloc((size_t)CAP * 4);
  unsigned short* sorted_x = (unsigned short*)alloc((size_t)CAP * DIM * 2);
  unsigned short* inter    = (unsigned short*)alloc((size_t)CAP * MDIM * 2);
  unsigned short* W0t      = (unsigned short*)alloc((size_t)NE * MDIM * DIM * 2);
  unsigned short* W1t      = (unsigned short*)alloc((size_t)NE * MDIM * DIM * 2);
  unsigned short* Wot      = (unsigned short*)alloc((size_t)NE * DIM * MDIM * 2);

  hipMemsetAsync(d_out, 0, (size_t)out_size * sizeof(float), stream);
  hipMemsetAsync(d_ws, 0, 1024, stream);  // counts + fill (+offsets slack)

  router_kernel<<<T_TOK / 4, 256, 0, stream>>>(x, wg, counts, tok_eid, tok_w);
  scan_kernel<<<1, 64, 0, stream>>>(counts, offsets);
  dispatch_kernel<<<T_TOK, 256, 0, stream>>>(x, tok_eid, tok_w, offsets, fill,
                                             row_token, row_weight, sorted_x);
  // wi_0 [E][D][M] -> W0t [E][M][D]; wi_1 likewise; wo [E][M][D] -> Wot [E][D][M]
  transpose_cast_kernel<<<dim3(MDIM / 32, DIM / 32, NE), 256, 0, stream>>>(wi0, W0t, DIM, MDIM);
  transpose_cast_kernel<<<dim3(MDIM / 32, DIM / 32, NE), 256, 0, stream>>>(wi1, W1t, DIM, MDIM);
  transpose_cast_kernel<<<dim3(DIM / 32, MDIM / 32, NE), 256, 0, stream>>>(wo, Wot, MDIM, DIM);

  gemm12_kernel<<<dim3(64, MDIM / 64, NE), 256, 0, stream>>>(sorted_x, W0t, W1t, offsets, inter);
  gemm3_kernel<<<dim3(64, DIM / 128, NE), 256, 0, stream>>>(inter, Wot, offsets,
                                                            row_token, row_weight, out);
}

// Round 2
// 919.262 us; speedup vs baseline: 1.2336x; 1.2336x over previous
//
#include <hip/hip_runtime.h>
#include <hip/hip_bf16.h>
#include <math.h>

// Problem dims (fixed by reference)
#define T_TOK 8192          // B*S tokens
#define DIM   2048          // D
#define NE    8             // experts
#define MDIM  1024          // intermediate
#define TK    16384         // T*K token copies
#define CAP   (TK + 128)    // slack rows so edge tiles can over-read safely
#define MAXTILES 136        // sum_e ceil(cnt_e/128) <= 128 + 8

typedef __attribute__((ext_vector_type(8))) short bf16x8;
typedef __attribute__((ext_vector_type(4))) float f32x4;

typedef __attribute__((address_space(3))) unsigned char* lds_ptr_t;
typedef const __attribute__((address_space(1))) unsigned char* glb_ptr_t;

__device__ __forceinline__ unsigned short f2bf(float f) {
  union { float f; unsigned u; } v; v.f = f;
  unsigned r = v.u + 0x7fffu + ((v.u >> 16) & 1u);  // round-to-nearest-even
  return (unsigned short)(r >> 16);
}

__device__ __forceinline__ void gload_lds16(const void* g, void* l) {
  // each lane loads 16B from its own global addr; lands at lds_base + lane*16
  __builtin_amdgcn_global_load_lds((glb_ptr_t)g, (lds_ptr_t)l, 16, 0, 0);
}

// ---------------- router: fp64 logits, top-2, softmax weights ----------------
__global__ __launch_bounds__(256) void router_kernel(
    const float* __restrict__ x, const float* __restrict__ wg,
    int* __restrict__ counts, int* __restrict__ tok_eid, float* __restrict__ tok_w) {
  int gwave = (blockIdx.x * 256 + threadIdx.x) >> 6;
  int lane = threadIdx.x & 63;
  if (gwave >= T_TOK) return;
  const float* xr = x + (size_t)gwave * DIM;
  double acc[NE];
#pragma unroll
  for (int e = 0; e < NE; e++) acc[e] = 0.0;
  for (int d = lane; d < DIM; d += 64) {
    double xv = (double)xr[d];
    const float* wr = wg + (size_t)d * NE;
#pragma unroll
    for (int e = 0; e < NE; e++) acc[e] += xv * (double)wr[e];
  }
#pragma unroll
  for (int e = 0; e < NE; e++) {
    double v = acc[e];
#pragma unroll
    for (int off = 32; off > 0; off >>= 1) v += __shfl_down(v, off, 64);
    acc[e] = v;
  }
  if (lane == 0) {
    int b0 = 0; double l0 = acc[0];
#pragma unroll
    for (int e = 1; e < NE; e++) { if (acc[e] > l0) { l0 = acc[e]; b0 = e; } }
    int b1 = -1; double l1 = -1.0e300;
#pragma unroll
    for (int e = 0; e < NE; e++) { if (e != b0 && acc[e] > l1) { l1 = acc[e]; b1 = e; } }
    double w0 = 1.0 / (1.0 + exp(l1 - l0));
    tok_eid[2 * gwave]     = b0;
    tok_eid[2 * gwave + 1] = b1;
    tok_w[2 * gwave]     = (float)w0;
    tok_w[2 * gwave + 1] = (float)(1.0 - w0);
    atomicAdd(&counts[b0], 1);
    atomicAdd(&counts[b1], 1);
  }
}

// ---------------- plan: expert row offsets + dense 128-row tile prefix ------
__global__ void scan_kernel(const int* __restrict__ counts, int* __restrict__ offsets,
                            int* __restrict__ tstart) {
  if (threadIdx.x == 0) {
    int s = 0, ts = 0;
    for (int e = 0; e < NE; e++) {
      offsets[e] = s; s += counts[e];
      tstart[e] = ts; ts += (counts[e] + 127) / 128;
    }
    offsets[NE] = s;
    tstart[NE] = ts;
  }
}

// ---------------- dispatch: slot assignment + gather x -> sorted_x (bf16) ----
__global__ __launch_bounds__(256) void dispatch_kernel(
    const float* __restrict__ x, const int* __restrict__ tok_eid,
    const float* __restrict__ tok_w, const int* __restrict__ offsets,
    int* __restrict__ fill, int* __restrict__ tok_slot,
    unsigned short* __restrict__ sorted_x) {
  int t = blockIdx.x;
  __shared__ int slots[2];
  if (threadIdx.x < 2) {
    int e = tok_eid[2 * t + threadIdx.x];
    int pos = atomicAdd(&fill[e], 1);
    int slot = offsets[e] + pos;
    slots[threadIdx.x] = slot;
    tok_slot[2 * t + threadIdx.x] = slot;
  }
  __syncthreads();
  size_t s0 = (size_t)slots[0] * DIM, s1 = (size_t)slots[1] * DIM;
  const float4* xr = (const float4*)(x + (size_t)t * DIM);
#pragma unroll
  for (int i = threadIdx.x; i < DIM / 4; i += 256) {
    float4 v = xr[i];
    ushort4 b;
    b.x = f2bf(v.x); b.y = f2bf(v.y); b.z = f2bf(v.z); b.w = f2bf(v.w);
    *(ushort4*)(sorted_x + s0 + (size_t)i * 4) = b;
    *(ushort4*)(sorted_x + s1 + (size_t)i * 4) = b;
  }
}

// ---------------- weight cast + transpose: f32 [R][C] -> bf16 [C][R] --------
__global__ __launch_bounds__(256) void transpose_cast_kernel(
    const float* __restrict__ in, unsigned short* __restrict__ out, int R, int C) {
  __shared__ unsigned short tile[32][33];
  int e = blockIdx.z;
  const float* inp = in + (size_t)e * R * C;
  unsigned short* outp = out + (size_t)e * R * C;
  int c0 = blockIdx.x * 32, r0 = blockIdx.y * 32;
  int tx = threadIdx.x & 31, ty = threadIdx.x >> 5;  // ty 0..7
#pragma unroll
  for (int i = 0; i < 32; i += 8)
    tile[ty + i][tx] = f2bf(inp[(size_t)(r0 + ty + i) * C + (c0 + tx)]);
  __syncthreads();
#pragma unroll
  for (int i = 0; i < 32; i += 8)
    outp[(size_t)(c0 + ty + i) * R + (r0 + tx)] = tile[tx][ty + i];
}

// ---------------- GEMM12: inter = silu(A@wi0) * (A@wi1), bf16 MFMA ----------
// A: sorted_x [CAP][DIM] bf16 row-major; W0t/W1t: [NE][MDIM][DIM] bf16 (N-major, K-contig)
// Dense tile grid: blockIdx.x is a flat 128-row tile index; expert found via tstart[].
__global__ __launch_bounds__(256) void gemm12_kernel(
    const unsigned short* __restrict__ A, const unsigned short* __restrict__ W0t,
    const unsigned short* __restrict__ W1t, const int* __restrict__ offsets,
    const int* __restrict__ tstart, unsigned short* __restrict__ inter) {
  int bx = blockIdx.x;
  if (bx >= tstart[NE]) return;
  int e = 0;
#pragma unroll
  for (int k = 1; k < NE; k++) if (tstart[k] <= bx) e = k;
  int row0 = offsets[e], row_end = offsets[e + 1];
  int tile_r0 = row0 + (bx - tstart[e]) * 128;
  if (tile_r0 >= row_end) return;
  int col0 = blockIdx.y * 64;

  __shared__ unsigned short As[128 * 32];
  __shared__ unsigned short B0s[64 * 32];
  __shared__ unsigned short B1s[64 * 32];

  int tid = threadIdx.x;
  int wave = tid >> 6, lane = tid & 63;
  int wm = wave >> 1, wn = wave & 1;  // wave tile: 64 rows x 32 cols (per matrix)

  const unsigned short* B0 = W0t + ((size_t)e * MDIM + col0) * DIM;
  const unsigned short* B1 = W1t + ((size_t)e * MDIM + col0) * DIM;

  f32x4 acc0[4][2], acc1[4][2];
#pragma unroll
  for (int i = 0; i < 4; i++)
#pragma unroll
    for (int j = 0; j < 2; j++) {
      acc0[i][j] = (f32x4){0.f, 0.f, 0.f, 0.f};
      acc1[i][j] = (f32x4){0.f, 0.f, 0.f, 0.f};
    }

  int lrow = lane >> 2;            // 0..15
  int lkoff = (lane & 3) * 8;      // element offset within 32-wide K chunk

  for (int k0 = 0; k0 < DIM; k0 += 32) {
#pragma unroll
    for (int c = 0; c < 2; c++) {
      int r = wave * 32 + c * 16 + lrow;
      gload_lds16(A + (size_t)(tile_r0 + r) * DIM + k0 + lkoff,
                  &As[(wave * 32 + c * 16) * 32]);
    }
    {
      int r = wave * 16 + lrow;
      gload_lds16(B0 + (size_t)r * DIM + k0 + lkoff, &B0s[(wave * 16) * 32]);
      gload_lds16(B1 + (size_t)r * DIM + k0 + lkoff, &B1s[(wave * 16) * 32]);
    }
    __syncthreads();
    bf16x8 af[4], b0f[2], b1f[2];
#pragma unroll
    for (int mi = 0; mi < 4; mi++)
      af[mi] = *(const bf16x8*)&As[(wm * 64 + mi * 16 + (lane & 15)) * 32 + (lane >> 4) * 8];
#pragma unroll
    for (int ni = 0; ni < 2; ni++) {
      b0f[ni] = *(const bf16x8*)&B0s[(wn * 32 + ni * 16 + (lane & 15)) * 32 + (lane >> 4) * 8];
      b1f[ni] = *(const bf16x8*)&B1s[(wn * 32 + ni * 16 + (lane & 15)) * 32 + (lane >> 4) * 8];
    }
#pragma unroll
    for (int mi = 0; mi < 4; mi++)
#pragma unroll
      for (int ni = 0; ni < 2; ni++) {
        acc0[mi][ni] = __builtin_amdgcn_mfma_f32_16x16x32_bf16(af[mi], b0f[ni], acc0[mi][ni], 0, 0, 0);
        acc1[mi][ni] = __builtin_amdgcn_mfma_f32_16x16x32_bf16(af[mi], b1f[ni], acc1[mi][ni], 0, 0, 0);
      }
    __syncthreads();
  }
  // epilogue: silu(h0)*h1 -> inter (bf16). C/D: col=lane&15, row=(lane>>4)*4+reg
#pragma unroll
  for (int mi = 0; mi < 4; mi++)
#pragma unroll
    for (int reg = 0; reg < 4; reg++) {
      int grow = tile_r0 + wm * 64 + mi * 16 + (lane >> 4) * 4 + reg;
      if (grow < row_end) {
#pragma unroll
        for (int ni = 0; ni < 2; ni++) {
          float h0 = acc0[mi][ni][reg];
          float h1 = acc1[mi][ni][reg];
          float g = h0 / (1.0f + __expf(-h0));
          int col = col0 + wn * 32 + ni * 16 + (lane & 15);
          inter[(size_t)grow * MDIM + col] = f2bf(g * h1);
        }
      }
    }
}

// ---------------- GEMM3: out_sorted = inter @ wo  (plain f32 stores) --------
// A: inter [CAP][MDIM] bf16; Wot: [NE][DIM][MDIM] bf16 (N-major, K-contig)
__global__ __launch_bounds__(256) void gemm3_kernel(
    const unsigned short* __restrict__ A, const unsigned short* __restrict__ Wot,
    const int* __restrict__ offsets, const int* __restrict__ tstart,
    float* __restrict__ out_sorted) {
  int bx = blockIdx.x;
  if (bx >= tstart[NE]) return;
  int e = 0;
#pragma unroll
  for (int k = 1; k < NE; k++) if (tstart[k] <= bx) e = k;
  int row0 = offsets[e], row_end = offsets[e + 1];
  int tile_r0 = row0 + (bx - tstart[e]) * 128;
  if (tile_r0 >= row_end) return;
  int col0 = blockIdx.y * 128;

  __shared__ unsigned short As[128 * 32];
  __shared__ unsigned short Bs[128 * 32];

  int tid = threadIdx.x;
  int wave = tid >> 6, lane = tid & 63;
  int wm = wave >> 1, wn = wave & 1;  // wave tile: 64 x 64

  const unsigned short* B = Wot + ((size_t)e * DIM + col0) * MDIM;

  f32x4 acc[4][4];
#pragma unroll
  for (int i = 0; i < 4; i++)
#pragma unroll
    for (int j = 0; j < 4; j++) acc[i][j] = (f32x4){0.f, 0.f, 0.f, 0.f};

  int lrow = lane >> 2;
  int lkoff = (lane & 3) * 8;

  for (int k0 = 0; k0 < MDIM; k0 += 32) {
#pragma unroll
    for (int c = 0; c < 2; c++) {
      int r = wave * 32 + c * 16 + lrow;
      gload_lds16(A + (size_t)(tile_r0 + r) * MDIM + k0 + lkoff,
                  &As[(wave * 32 + c * 16) * 32]);
      gload_lds16(B + (size_t)r * MDIM + k0 + lkoff,
                  &Bs[(wave * 32 + c * 16) * 32]);
    }
    __syncthreads();
    bf16x8 af[4], bfr[4];
#pragma unroll
    for (int mi = 0; mi < 4; mi++)
      af[mi] = *(const bf16x8*)&As[(wm * 64 + mi * 16 + (lane & 15)) * 32 + (lane >> 4) * 8];
#pragma unroll
    for (int ni = 0; ni < 4; ni++)
      bfr[ni] = *(const bf16x8*)&Bs[(wn * 64 + ni * 16 + (lane & 15)) * 32 + (lane >> 4) * 8];
#pragma unroll
    for (int mi = 0; mi < 4; mi++)
#pragma unroll
      for (int ni = 0; ni < 4; ni++)
        acc[mi][ni] = __builtin_amdgcn_mfma_f32_16x16x32_bf16(af[mi], bfr[ni], acc[mi][ni], 0, 0, 0);
    __syncthreads();
  }
  // epilogue: plain f32 stores (no atomics)
#pragma unroll
  for (int mi = 0; mi < 4; mi++)
#pragma unroll
    for (int reg = 0; reg < 4; reg++) {
      int grow = tile_r0 + wm * 64 + mi * 16 + (lane >> 4) * 4 + reg;
      if (grow < row_end) {
        float* orow = out_sorted + (size_t)grow * DIM + col0 + wn * 64 + (lane & 15);
#pragma unroll
        for (int ni = 0; ni < 4; ni++)
          orow[ni * 16] = acc[mi][ni][reg];
      }
    }
}

// ---------------- combine: out[t] = w0*os[slot0] + w1*os[slot1] -------------
__global__ __launch_bounds__(256) void combine_kernel(
    const float* __restrict__ os, const int* __restrict__ tok_slot,
    const float* __restrict__ tok_w, float* __restrict__ out) {
  int t = blockIdx.x * 4 + (threadIdx.x >> 6);
  int lane = threadIdx.x & 63;
  int s0 = tok_slot[2 * t], s1 = tok_slot[2 * t + 1];
  float w0 = tok_w[2 * t], w1 = tok_w[2 * t + 1];
  const float4* a = (const float4*)(os + (size_t)s0 * DIM);
  const float4* b = (const float4*)(os + (size_t)s1 * DIM);
  float4* o = (float4*)(out + (size_t)t * DIM);
#pragma unroll
  for (int i = lane; i < DIM / 4; i += 64) {
    float4 va = a[i], vb = b[i];
    float4 r;
    r.x = w0 * va.x + w1 * vb.x;
    r.y = w0 * va.y + w1 * vb.y;
    r.z = w0 * va.z + w1 * vb.z;
    r.w = w0 * va.w + w1 * vb.w;
    o[i] = r;
  }
}

// ---------------------------------------------------------------------------
extern "C" void kernel_launch(void* const* d_in, const int* in_sizes, int n_in,
                              void* d_out, int out_size, void* d_ws, size_t ws_size,
                              hipStream_t stream) {
  const float* x   = (const float*)d_in[0];
  const float* wg  = (const float*)d_in[1];
  const float* wi0 = (const float*)d_in[2];
  const float* wi1 = (const float*)d_in[3];
  const float* wo  = (const float*)d_in[4];
  float* out = (float*)d_out;

  char* ws = (char*)d_ws;
  size_t off = 0;
  auto alloc = [&](size_t bytes) -> void* {
    void* p = ws + off;
    off = (off + bytes + 255) & ~(size_t)255;
    return p;
  };
  int*   counts   = (int*)alloc(NE * 4);
  int*   fill     = (int*)alloc(NE * 4);
  int*   offsets  = (int*)alloc((NE + 1) * 4);
  int*   tstart   = (int*)alloc((NE + 1) * 4);
  int*   tok_eid  = (int*)alloc((size_t)2 * T_TOK * 4);
  float* tok_w    = (float*)alloc((size_t)2 * T_TOK * 4);
  int*   tok_slot = (int*)alloc((size_t)2 * T_TOK * 4);
  unsigned short* inter    = (unsigned short*)alloc((size_t)CAP * MDIM * 2);
  // sorted_x + W0t + W1t form one contiguous 134.77 MB window; after gemm12
  // they are dead and out_sorted (16384*DIM*4 = 134.22 MB) aliases the window.
  unsigned short* sorted_x = (unsigned short*)alloc((size_t)CAP * DIM * 2);
  unsigned short* W0t      = (unsigned short*)alloc((size_t)NE * MDIM * DIM * 2);
  unsigned short* W1t      = (unsigned short*)alloc((size_t)NE * MDIM * DIM * 2);
  unsigned short* Wot      = (unsigned short*)alloc((size_t)NE * DIM * MDIM * 2);
  float* out_sorted = (float*)sorted_x;  // alias (see above)

  hipMemsetAsync(d_ws, 0, 1024, stream);  // zero counts/fill/offsets/tstart

  router_kernel<<<T_TOK / 4, 256, 0, stream>>>(x, wg, counts, tok_eid, tok_w);
  scan_kernel<<<1, 64, 0, stream>>>(counts, offsets, tstart);
  dispatch_kernel<<<T_TOK, 256, 0, stream>>>(x, tok_eid, tok_w, offsets, fill,
                                             tok_slot, sorted_x);
  // wi_0 [E][D][M] -> W0t [E][M][D]; wi_1 likewise; wo [E][M][D] -> Wot [E][D][M]
  transpose_cast_kernel<<<dim3(MDIM / 32, DIM / 32, NE), 256, 0, stream>>>(wi0, W0t, DIM, MDIM);
  transpose_cast_kernel<<<dim3(MDIM / 32, DIM / 32, NE), 256, 0, stream>>>(wi1, W1t, DIM, MDIM);
  transpose_cast_kernel<<<dim3(DIM / 32, MDIM / 32, NE), 256, 0, stream>>>(wo, Wot, MDIM, DIM);

  gemm12_kernel<<<dim3(MAXTILES, MDIM / 64, 1), 256, 0, stream>>>(
      sorted_x, W0t, W1t, offsets, tstart, inter);
  gemm3_kernel<<<dim3(MAXTILES, DIM / 128, 1), 256, 0, stream>>>(
      inter, Wot, offsets, tstart, out_sorted);
  combine_kernel<<<T_TOK / 4, 256, 0, stream>>>(out_sorted, tok_slot, tok_w, out);
}

// Round 3
// 915.020 us; speedup vs baseline: 1.2393x; 1.0046x over previous
//
#include <hip/hip_runtime.h>
#include <hip/hip_bf16.h>
#include <math.h>

// Problem dims (fixed by reference)
#define T_TOK 8192          // B*S tokens
#define DIM   2048          // D
#define NE    8             // experts
#define MDIM  1024          // intermediate
#define TK    16384         // T*K token copies
#define CAP   (TK + 128)    // slack rows so edge tiles can over-read safely
#define MAXTILES 136        // sum_e ceil(cnt_e/128) <= 128 + 8

typedef __attribute__((ext_vector_type(8))) short bf16x8;
typedef __attribute__((ext_vector_type(4))) float f32x4;

typedef __attribute__((address_space(3))) unsigned char* lds_ptr_t;
typedef const __attribute__((address_space(1))) unsigned char* glb_ptr_t;

__device__ __forceinline__ unsigned short f2bf(float f) {
  union { float f; unsigned u; } v; v.f = f;
  unsigned r = v.u + 0x7fffu + ((v.u >> 16) & 1u);  // round-to-nearest-even
  return (unsigned short)(r >> 16);
}

__device__ __forceinline__ void gload_lds16(const void* g, void* l) {
  // each lane loads 16B from its own global addr; lands at lds_base + lane*16
  __builtin_amdgcn_global_load_lds((glb_ptr_t)g, (lds_ptr_t)l, 16, 0, 0);
}

// ---------------- router: fp64 logits, top-2, softmax weights ----------------
// LDS-staged wgT (2 phases x 32KB), 4 tokens/wave, float4 coalesced x loads.
__global__ __launch_bounds__(256) void router_kernel(
    const float* __restrict__ x, const float* __restrict__ wg,
    int* __restrict__ counts, int* __restrict__ tok_eid, float* __restrict__ tok_w) {
  __shared__ float wgT[NE][1024];  // 32 KB, one D-half at a time
  int tid = threadIdx.x;
  int wave = tid >> 6, lane = tid & 63;
  int t0 = blockIdx.x * 16 + wave * 4;  // 512 blocks x 4 waves x 4 tokens = 8192

  double acc[4][NE];
#pragma unroll
  for (int tt = 0; tt < 4; tt++)
#pragma unroll
    for (int e = 0; e < NE; e++) acc[tt][e] = 0.0;

  for (int p = 0; p < 2; p++) {
    __syncthreads();  // previous phase's reads done before restage
    // stage wg[d][e] for d in [p*1024, p*1024+1024) -> wgT[e][d-p*1024]
#pragma unroll
    for (int j = tid; j < 2048; j += 256) {  // 2048 float4s = 1024 rows x 8 floats
      float4 v = ((const float4*)wg)[p * 2048 + j];
      int d = j >> 1, h = (j & 1) * 4;
      wgT[h + 0][d] = v.x;
      wgT[h + 1][d] = v.y;
      wgT[h + 2][d] = v.z;
      wgT[h + 3][d] = v.w;
    }
    __syncthreads();
#pragma unroll
    for (int it = 0; it < 4; it++) {
      int dd = it * 256 + lane * 4;        // local d within phase
      int gd = p * 1024 + dd;              // global d
      float4 wf[NE];
#pragma unroll
      for (int e = 0; e < NE; e++) wf[e] = *(const float4*)&wgT[e][dd];
#pragma unroll
      for (int tt = 0; tt < 4; tt++) {
        float4 xv = *(const float4*)(x + (size_t)(t0 + tt) * DIM + gd);
#pragma unroll
        for (int e = 0; e < NE; e++) {
          acc[tt][e] += (double)xv.x * (double)wf[e].x;
          acc[tt][e] += (double)xv.y * (double)wf[e].y;
          acc[tt][e] += (double)xv.z * (double)wf[e].z;
          acc[tt][e] += (double)xv.w * (double)wf[e].w;
        }
      }
    }
  }
  // wave butterfly reduce each (token, expert) over 64 lanes
#pragma unroll
  for (int tt = 0; tt < 4; tt++)
#pragma unroll
    for (int e = 0; e < NE; e++) {
      double v = acc[tt][e];
#pragma unroll
      for (int off = 32; off > 0; off >>= 1) v += __shfl_down(v, off, 64);
      acc[tt][e] = v;
    }
  if (lane == 0) {
#pragma unroll
    for (int tt = 0; tt < 4; tt++) {
      int t = t0 + tt;
      int b0 = 0; double l0 = acc[tt][0];
#pragma unroll
      for (int e = 1; e < NE; e++) { if (acc[tt][e] > l0) { l0 = acc[tt][e]; b0 = e; } }
      int b1 = -1; double l1 = -1.0e300;
#pragma unroll
      for (int e = 0; e < NE; e++) { if (e != b0 && acc[tt][e] > l1) { l1 = acc[tt][e]; b1 = e; } }
      double w0 = 1.0 / (1.0 + exp(l1 - l0));
      tok_eid[2 * t]     = b0;
      tok_eid[2 * t + 1] = b1;
      tok_w[2 * t]     = (float)w0;
      tok_w[2 * t + 1] = (float)(1.0 - w0);
      atomicAdd(&counts[b0], 1);
      atomicAdd(&counts[b1], 1);
    }
  }
}

// ---------------- plan: expert row offsets + dense 128-row tile prefix ------
__global__ void scan_kernel(const int* __restrict__ counts, int* __restrict__ offsets,
                            int* __restrict__ tstart) {
  if (threadIdx.x == 0) {
    int s = 0, ts = 0;
    for (int e = 0; e < NE; e++) {
      offsets[e] = s; s += counts[e];
      tstart[e] = ts; ts += (counts[e] + 127) / 128;
    }
    offsets[NE] = s;
    tstart[NE] = ts;
  }
}

// ---------------- dispatch: slot assignment + gather x -> sorted_x (bf16) ----
__global__ __launch_bounds__(256) void dispatch_kernel(
    const float* __restrict__ x, const int* __restrict__ tok_eid,
    const float* __restrict__ tok_w, const int* __restrict__ offsets,
    int* __restrict__ fill, int* __restrict__ tok_slot,
    unsigned short* __restrict__ sorted_x) {
  int t = blockIdx.x;
  __shared__ int slots[2];
  if (threadIdx.x < 2) {
    int e = tok_eid[2 * t + threadIdx.x];
    int pos = atomicAdd(&fill[e], 1);
    int slot = offsets[e] + pos;
    slots[threadIdx.x] = slot;
    tok_slot[2 * t + threadIdx.x] = slot;
  }
  __syncthreads();
  size_t s0 = (size_t)slots[0] * DIM, s1 = (size_t)slots[1] * DIM;
  const float4* xr = (const float4*)(x + (size_t)t * DIM);
#pragma unroll
  for (int i = threadIdx.x; i < DIM / 4; i += 256) {
    float4 v = xr[i];
    ushort4 b;
    b.x = f2bf(v.x); b.y = f2bf(v.y); b.z = f2bf(v.z); b.w = f2bf(v.w);
    *(ushort4*)(sorted_x + s0 + (size_t)i * 4) = b;
    *(ushort4*)(sorted_x + s1 + (size_t)i * 4) = b;
  }
}

// ---------------- weight cast + transpose: f32 [R][C] -> bf16 [C][R] --------
__global__ __launch_bounds__(256) void transpose_cast_kernel(
    const float* __restrict__ in, unsigned short* __restrict__ out, int R, int C) {
  __shared__ unsigned short tile[32][33];
  int e = blockIdx.z;
  const float* inp = in + (size_t)e * R * C;
  unsigned short* outp = out + (size_t)e * R * C;
  int c0 = blockIdx.x * 32, r0 = blockIdx.y * 32;
  int tx = threadIdx.x & 31, ty = threadIdx.x >> 5;  // ty 0..7
#pragma unroll
  for (int i = 0; i < 32; i += 8)
    tile[ty + i][tx] = f2bf(inp[(size_t)(r0 + ty + i) * C + (c0 + tx)]);
  __syncthreads();
#pragma unroll
  for (int i = 0; i < 32; i += 8)
    outp[(size_t)(c0 + ty + i) * R + (r0 + tx)] = tile[tx][ty + i];
}

// ---------------- GEMM12: inter = silu(A@wi0) * (A@wi1), bf16 MFMA ----------
// A: sorted_x [CAP][DIM] bf16 row-major; W0t/W1t: [NE][MDIM][DIM] bf16 (N-major, K-contig)
// Dense tile grid: blockIdx.x is a flat 128-row tile index; expert found via tstart[].
__global__ __launch_bounds__(256) void gemm12_kernel(
    const unsigned short* __restrict__ A, const unsigned short* __restrict__ W0t,
    const unsigned short* __restrict__ W1t, const int* __restrict__ offsets,
    const int* __restrict__ tstart, unsigned short* __restrict__ inter) {
  int bx = blockIdx.x;
  if (bx >= tstart[NE]) return;
  int e = 0;
#pragma unroll
  for (int k = 1; k < NE; k++) if (tstart[k] <= bx) e = k;
  int row0 = offsets[e], row_end = offsets[e + 1];
  int tile_r0 = row0 + (bx - tstart[e]) * 128;
  if (tile_r0 >= row_end) return;
  int col0 = blockIdx.y * 64;

  __shared__ unsigned short As[128 * 32];
  __shared__ unsigned short B0s[64 * 32];
  __shared__ unsigned short B1s[64 * 32];

  int tid = threadIdx.x;
  int wave = tid >> 6, lane = tid & 63;
  int wm = wave >> 1, wn = wave & 1;  // wave tile: 64 rows x 32 cols (per matrix)

  const unsigned short* B0 = W0t + ((size_t)e * MDIM + col0) * DIM;
  const unsigned short* B1 = W1t + ((size_t)e * MDIM + col0) * DIM;

  f32x4 acc0[4][2], acc1[4][2];
#pragma unroll
  for (int i = 0; i < 4; i++)
#pragma unroll
    for (int j = 0; j < 2; j++) {
      acc0[i][j] = (f32x4){0.f, 0.f, 0.f, 0.f};
      acc1[i][j] = (f32x4){0.f, 0.f, 0.f, 0.f};
    }

  int lrow = lane >> 2;            // 0..15
  int lkoff = (lane & 3) * 8;      // element offset within 32-wide K chunk

  for (int k0 = 0; k0 < DIM; k0 += 32) {
#pragma unroll
    for (int c = 0; c < 2; c++) {
      int r = wave * 32 + c * 16 + lrow;
      gload_lds16(A + (size_t)(tile_r0 + r) * DIM + k0 + lkoff,
                  &As[(wave * 32 + c * 16) * 32]);
    }
    {
      int r = wave * 16 + lrow;
      gload_lds16(B0 + (size_t)r * DIM + k0 + lkoff, &B0s[(wave * 16) * 32]);
      gload_lds16(B1 + (size_t)r * DIM + k0 + lkoff, &B1s[(wave * 16) * 32]);
    }
    __syncthreads();
    bf16x8 af[4], b0f[2], b1f[2];
#pragma unroll
    for (int mi = 0; mi < 4; mi++)
      af[mi] = *(const bf16x8*)&As[(wm * 64 + mi * 16 + (lane & 15)) * 32 + (lane >> 4) * 8];
#pragma unroll
    for (int ni = 0; ni < 2; ni++) {
      b0f[ni] = *(const bf16x8*)&B0s[(wn * 32 + ni * 16 + (lane & 15)) * 32 + (lane >> 4) * 8];
      b1f[ni] = *(const bf16x8*)&B1s[(wn * 32 + ni * 16 + (lane & 15)) * 32 + (lane >> 4) * 8];
    }
#pragma unroll
    for (int mi = 0; mi < 4; mi++)
#pragma unroll
      for (int ni = 0; ni < 2; ni++) {
        acc0[mi][ni] = __builtin_amdgcn_mfma_f32_16x16x32_bf16(af[mi], b0f[ni], acc0[mi][ni], 0, 0, 0);
        acc1[mi][ni] = __builtin_amdgcn_mfma_f32_16x16x32_bf16(af[mi], b1f[ni], acc1[mi][ni], 0, 0, 0);
      }
    __syncthreads();
  }
  // epilogue: silu(h0)*h1 -> inter (bf16). C/D: col=lane&15, row=(lane>>4)*4+reg
#pragma unroll
  for (int mi = 0; mi < 4; mi++)
#pragma unroll
    for (int reg = 0; reg < 4; reg++) {
      int grow = tile_r0 + wm * 64 + mi * 16 + (lane >> 4) * 4 + reg;
      if (grow < row_end) {
#pragma unroll
        for (int ni = 0; ni < 2; ni++) {
          float h0 = acc0[mi][ni][reg];
          float h1 = acc1[mi][ni][reg];
          float g = h0 / (1.0f + __expf(-h0));
          int col = col0 + wn * 32 + ni * 16 + (lane & 15);
          inter[(size_t)grow * MDIM + col] = f2bf(g * h1);
        }
      }
    }
}

// ---------------- GEMM3: out_sorted = inter @ wo  (plain f32 stores) --------
// A: inter [CAP][MDIM] bf16; Wot: [NE][DIM][MDIM] bf16 (N-major, K-contig)
__global__ __launch_bounds__(256) void gemm3_kernel(
    const unsigned short* __restrict__ A, const unsigned short* __restrict__ Wot,
    const int* __restrict__ offsets, const int* __restrict__ tstart,
    float* __restrict__ out_sorted) {
  int bx = blockIdx.x;
  if (bx >= tstart[NE]) return;
  int e = 0;
#pragma unroll
  for (int k = 1; k < NE; k++) if (tstart[k] <= bx) e = k;
  int row0 = offsets[e], row_end = offsets[e + 1];
  int tile_r0 = row0 + (bx - tstart[e]) * 128;
  if (tile_r0 >= row_end) return;
  int col0 = blockIdx.y * 128;

  __shared__ unsigned short As[128 * 32];
  __shared__ unsigned short Bs[128 * 32];

  int tid = threadIdx.x;
  int wave = tid >> 6, lane = tid & 63;
  int wm = wave >> 1, wn = wave & 1;  // wave tile: 64 x 64

  const unsigned short* B = Wot + ((size_t)e * DIM + col0) * MDIM;

  f32x4 acc[4][4];
#pragma unroll
  for (int i = 0; i < 4; i++)
#pragma unroll
    for (int j = 0; j < 4; j++) acc[i][j] = (f32x4){0.f, 0.f, 0.f, 0.f};

  int lrow = lane >> 2;
  int lkoff = (lane & 3) * 8;

  for (int k0 = 0; k0 < MDIM; k0 += 32) {
#pragma unroll
    for (int c = 0; c < 2; c++) {
      int r = wave * 32 + c * 16 + lrow;
      gload_lds16(A + (size_t)(tile_r0 + r) * MDIM + k0 + lkoff,
                  &As[(wave * 32 + c * 16) * 32]);
      gload_lds16(B + (size_t)r * MDIM + k0 + lkoff,
                  &Bs[(wave * 32 + c * 16) * 32]);
    }
    __syncthreads();
    bf16x8 af[4], bfr[4];
#pragma unroll
    for (int mi = 0; mi < 4; mi++)
      af[mi] = *(const bf16x8*)&As[(wm * 64 + mi * 16 + (lane & 15)) * 32 + (lane >> 4) * 8];
#pragma unroll
    for (int ni = 0; ni < 4; ni++)
      bfr[ni] = *(const bf16x8*)&Bs[(wn * 64 + ni * 16 + (lane & 15)) * 32 + (lane >> 4) * 8];
#pragma unroll
    for (int mi = 0; mi < 4; mi++)
#pragma unroll
      for (int ni = 0; ni < 4; ni++)
        acc[mi][ni] = __builtin_amdgcn_mfma_f32_16x16x32_bf16(af[mi], bfr[ni], acc[mi][ni], 0, 0, 0);
    __syncthreads();
  }
  // epilogue: plain f32 stores (no atomics)
#pragma unroll
  for (int mi = 0; mi < 4; mi++)
#pragma unroll
    for (int reg = 0; reg < 4; reg++) {
      int grow = tile_r0 + wm * 64 + mi * 16 + (lane >> 4) * 4 + reg;
      if (grow < row_end) {
        float* orow = out_sorted + (size_t)grow * DIM + col0 + wn * 64 + (lane & 15);
#pragma unroll
        for (int ni = 0; ni < 4; ni++)
          orow[ni * 16] = acc[mi][ni][reg];
      }
    }
}

// ---------------- combine: out[t] = w0*os[slot0] + w1*os[slot1] -------------
__global__ __launch_bounds__(256) void combine_kernel(
    const float* __restrict__ os, const int* __restrict__ tok_slot,
    const float* __restrict__ tok_w, float* __restrict__ out) {
  int t = blockIdx.x * 4 + (threadIdx.x >> 6);
  int lane = threadIdx.x & 63;
  int s0 = tok_slot[2 * t], s1 = tok_slot[2 * t + 1];
  float w0 = tok_w[2 * t], w1 = tok_w[2 * t + 1];
  const float4* a = (const float4*)(os + (size_t)s0 * DIM);
  const float4* b = (const float4*)(os + (size_t)s1 * DIM);
  float4* o = (float4*)(out + (size_t)t * DIM);
#pragma unroll
  for (int i = lane; i < DIM / 4; i += 64) {
    float4 va = a[i], vb = b[i];
    float4 r;
    r.x = w0 * va.x + w1 * vb.x;
    r.y = w0 * va.y + w1 * vb.y;
    r.z = w0 * va.z + w1 * vb.z;
    r.w = w0 * va.w + w1 * vb.w;
    o[i] = r;
  }
}

// ---------------------------------------------------------------------------
extern "C" void kernel_launch(void* const* d_in, const int* in_sizes, int n_in,
                              void* d_out, int out_size, void* d_ws, size_t ws_size,
                              hipStream_t stream) {
  const float* x   = (const float*)d_in[0];
  const float* wg  = (const float*)d_in[1];
  const float* wi0 = (const float*)d_in[2];
  const float* wi1 = (const float*)d_in[3];
  const float* wo  = (const float*)d_in[4];
  float* out = (float*)d_out;

  char* ws = (char*)d_ws;
  size_t off = 0;
  auto alloc = [&](size_t bytes) -> void* {
    void* p = ws + off;
    off = (off + bytes + 255) & ~(size_t)255;
    return p;
  };
  int*   counts   = (int*)alloc(NE * 4);
  int*   fill     = (int*)alloc(NE * 4);
  int*   offsets  = (int*)alloc((NE + 1) * 4);
  int*   tstart   = (int*)alloc((NE + 1) * 4);
  int*   tok_eid  = (int*)alloc((size_t)2 * T_TOK * 4);
  float* tok_w    = (float*)alloc((size_t)2 * T_TOK * 4);
  int*   tok_slot = (int*)alloc((size_t)2 * T_TOK * 4);
  unsigned short* inter    = (unsigned short*)alloc((size_t)CAP * MDIM * 2);
  // sorted_x + W0t + W1t form one contiguous 134.77 MB window; after gemm12
  // they are dead and out_sorted (16384*DIM*4 = 134.22 MB) aliases the window.
  unsigned short* sorted_x = (unsigned short*)alloc((size_t)CAP * DIM * 2);
  unsigned short* W0t      = (unsigned short*)alloc((size_t)NE * MDIM * DIM * 2);
  unsigned short* W1t      = (unsigned short*)alloc((size_t)NE * MDIM * DIM * 2);
  unsigned short* Wot      = (unsigned short*)alloc((size_t)NE * DIM * MDIM * 2);
  float* out_sorted = (float*)sorted_x;  // alias (see above)

  hipMemsetAsync(d_ws, 0, 1024, stream);  // zero counts/fill/offsets/tstart

  router_kernel<<<T_TOK / 16, 256, 0, stream>>>(x, wg, counts, tok_eid, tok_w);
  scan_kernel<<<1, 64, 0, stream>>>(counts, offsets, tstart);
  dispatch_kernel<<<T_TOK, 256, 0, stream>>>(x, tok_eid, tok_w, offsets, fill,
                                             tok_slot, sorted_x);
  // wi_0 [E][D][M] -> W0t [E][M][D]; wi_1 likewise; wo [E][M][D] -> Wot [E][D][M]
  transpose_cast_kernel<<<dim3(MDIM / 32, DIM / 32, NE), 256, 0, stream>>>(wi0, W0t, DIM, MDIM);
  transpose_cast_kernel<<<dim3(MDIM / 32, DIM / 32, NE), 256, 0, stream>>>(wi1, W1t, DIM, MDIM);
  transpose_cast_kernel<<<dim3(DIM / 32, MDIM / 32, NE), 256, 0, stream>>>(wo, Wot, MDIM, DIM);

  gemm12_kernel<<<dim3(MAXTILES, MDIM / 64, 1), 256, 0, stream>>>(
      sorted_x, W0t, W1t, offsets, tstart, inter);
  gemm3_kernel<<<dim3(MAXTILES, DIM / 128, 1), 256, 0, stream>>>(
      inter, Wot, offsets, tstart, out_sorted);
  combine_kernel<<<T_TOK / 4, 256, 0, stream>>>(out_sorted, tok_slot, tok_w, out);
}

// Round 4
// 693.083 us; speedup vs baseline: 1.6361x; 1.3202x over previous
//
#include <hip/hip_runtime.h>
#include <hip/hip_bf16.h>
#include <math.h>

// Problem dims (fixed by reference)
#define T_TOK 8192          // B*S tokens
#define DIM   2048          // D
#define NE    8             // experts
#define MDIM  1024          // intermediate
#define TK    16384         // T*K token copies
#define CAP   (TK + 128)    // slack rows so edge tiles can over-read safely
#define MAXTILES 136        // sum_e ceil(cnt_e/128) <= 128 + 8

typedef __attribute__((ext_vector_type(8))) short bf16x8;
typedef __attribute__((ext_vector_type(4))) float f32x4;

typedef __attribute__((address_space(3))) unsigned char* lds_ptr_t;
typedef const __attribute__((address_space(1))) unsigned char* glb_ptr_t;

__device__ __forceinline__ unsigned short f2bf(float f) {
  union { float f; unsigned u; } v; v.f = f;
  unsigned r = v.u + 0x7fffu + ((v.u >> 16) & 1u);  // round-to-nearest-even
  return (unsigned short)(r >> 16);
}

__device__ __forceinline__ void gload_lds16(const void* g, void* l) {
  // each lane loads 16B from its own global addr; lands at lds_base + lane*16
  __builtin_amdgcn_global_load_lds((glb_ptr_t)g, (lds_ptr_t)l, 16, 0, 0);
}

// ---------------- router: fp64 logits, top-2, softmax weights ----------------
// NO global atomics (16384 same-line atomicAdds serialized at ~32cyc = the
// entire 218us of rounds 1-3). Counting moved to plan_kernel.
__global__ __launch_bounds__(256) void router_kernel(
    const float* __restrict__ x, const float* __restrict__ wg,
    int* __restrict__ tok_eid, float* __restrict__ tok_w) {
  __shared__ float wgT[NE][1024];  // 32 KB, one D-half at a time
  int tid = threadIdx.x;
  int wave = tid >> 6, lane = tid & 63;
  int t0 = blockIdx.x * 16 + wave * 4;  // 512 blocks x 4 waves x 4 tokens = 8192

  double acc[4][NE];
#pragma unroll
  for (int tt = 0; tt < 4; tt++)
#pragma unroll
    for (int e = 0; e < NE; e++) acc[tt][e] = 0.0;

  for (int p = 0; p < 2; p++) {
    __syncthreads();  // previous phase's reads done before restage
#pragma unroll
    for (int j = tid; j < 2048; j += 256) {  // 2048 float4s = 1024 rows x 8 floats
      float4 v = ((const float4*)wg)[p * 2048 + j];
      int d = j >> 1, h = (j & 1) * 4;
      wgT[h + 0][d] = v.x;
      wgT[h + 1][d] = v.y;
      wgT[h + 2][d] = v.z;
      wgT[h + 3][d] = v.w;
    }
    __syncthreads();
#pragma unroll
    for (int it = 0; it < 4; it++) {
      int dd = it * 256 + lane * 4;        // local d within phase
      int gd = p * 1024 + dd;              // global d
      float4 wf[NE];
#pragma unroll
      for (int e = 0; e < NE; e++) wf[e] = *(const float4*)&wgT[e][dd];
#pragma unroll
      for (int tt = 0; tt < 4; tt++) {
        float4 xv = *(const float4*)(x + (size_t)(t0 + tt) * DIM + gd);
#pragma unroll
        for (int e = 0; e < NE; e++) {
          acc[tt][e] += (double)xv.x * (double)wf[e].x;
          acc[tt][e] += (double)xv.y * (double)wf[e].y;
          acc[tt][e] += (double)xv.z * (double)wf[e].z;
          acc[tt][e] += (double)xv.w * (double)wf[e].w;
        }
      }
    }
  }
  // wave butterfly reduce each (token, expert) over 64 lanes
#pragma unroll
  for (int tt = 0; tt < 4; tt++)
#pragma unroll
    for (int e = 0; e < NE; e++) {
      double v = acc[tt][e];
#pragma unroll
      for (int off = 32; off > 0; off >>= 1) v += __shfl_down(v, off, 64);
      acc[tt][e] = v;
    }
  if (lane == 0) {
#pragma unroll
    for (int tt = 0; tt < 4; tt++) {
      int t = t0 + tt;
      int b0 = 0; double l0 = acc[tt][0];
#pragma unroll
      for (int e = 1; e < NE; e++) { if (acc[tt][e] > l0) { l0 = acc[tt][e]; b0 = e; } }
      int b1 = -1; double l1 = -1.0e300;
#pragma unroll
      for (int e = 0; e < NE; e++) { if (e != b0 && acc[tt][e] > l1) { l1 = acc[tt][e]; b1 = e; } }
      double w0 = 1.0 / (1.0 + exp(l1 - l0));
      tok_eid[2 * t]     = b0;
      tok_eid[2 * t + 1] = b1;
      tok_w[2 * t]     = (float)w0;
      tok_w[2 * t + 1] = (float)(1.0 - w0);
    }
  }
}

// ---------------- plan: counting sort of tok_eid -> offsets/tstart/tok_slot --
// Single block, 256 threads, no global atomics. Thread th owns interleaved
// entries {i*256+th}; slot assignment is any bijection within each expert's
// range (downstream is permutation-invariant within an expert).
__global__ __launch_bounds__(256) void plan_kernel(
    const int* __restrict__ tok_eid, int* __restrict__ offsets,
    int* __restrict__ tstart, int* __restrict__ tok_slot) {
  __shared__ int cnt[256][NE];      // 8 KB
  __shared__ int pre[256][NE];      // 8 KB exclusive prefix per thread
  __shared__ int tot[NE];
  __shared__ int off_sh[NE + 1];
  int th = threadIdx.x;
  int c[NE];
#pragma unroll
  for (int k = 0; k < NE; k++) c[k] = 0;
  for (int i = 0; i < TK / 256; i++) {
    int e = tok_eid[i * 256 + th];
#pragma unroll
    for (int k = 0; k < NE; k++) c[k] += (e == k) ? 1 : 0;
  }
#pragma unroll
  for (int k = 0; k < NE; k++) cnt[th][k] = c[k];
  __syncthreads();
  if (th < NE) {  // 8 serial scanners, one per expert
    int run = 0;
#pragma unroll 4
    for (int i = 0; i < 256; i++) { pre[i][th] = run; run += cnt[i][th]; }
    tot[th] = run;
  }
  __syncthreads();
  if (th == 0) {
    int s = 0, ts = 0;
    for (int e = 0; e < NE; e++) {
      off_sh[e] = s; offsets[e] = s; s += tot[e];
      tstart[e] = ts; ts += (tot[e] + 127) / 128;
    }
    offsets[NE] = s; off_sh[NE] = s; tstart[NE] = ts;
  }
  __syncthreads();
  int b[NE];
#pragma unroll
  for (int k = 0; k < NE; k++) b[k] = off_sh[k] + pre[th][k];
  for (int i = 0; i < TK / 256; i++) {
    int idx = i * 256 + th;
    int e = tok_eid[idx];
    int slot = 0;
#pragma unroll
    for (int k = 0; k < NE; k++) {
      slot = (e == k) ? b[k] : slot;
      b[k] += (e == k) ? 1 : 0;
    }
    tok_slot[idx] = slot;
  }
}

// ---------------- dispatch: gather x -> sorted_x (bf16), atomic-free --------
__global__ __launch_bounds__(256) void dispatch_kernel(
    const float* __restrict__ x, const int* __restrict__ tok_slot,
    unsigned short* __restrict__ sorted_x) {
  int t = blockIdx.x;
  size_t s0 = (size_t)tok_slot[2 * t] * DIM;
  size_t s1 = (size_t)tok_slot[2 * t + 1] * DIM;
  const float4* xr = (const float4*)(x + (size_t)t * DIM);
#pragma unroll
  for (int i = threadIdx.x; i < DIM / 4; i += 256) {
    float4 v = xr[i];
    ushort4 b;
    b.x = f2bf(v.x); b.y = f2bf(v.y); b.z = f2bf(v.z); b.w = f2bf(v.w);
    *(ushort4*)(sorted_x + s0 + (size_t)i * 4) = b;
    *(ushort4*)(sorted_x + s1 + (size_t)i * 4) = b;
  }
}

// ---------------- weight cast + transpose: f32 [R][C] -> bf16 [C][R] --------
__global__ __launch_bounds__(256) void transpose_cast_kernel(
    const float* __restrict__ in, unsigned short* __restrict__ out, int R, int C) {
  __shared__ unsigned short tile[32][33];
  int e = blockIdx.z;
  const float* inp = in + (size_t)e * R * C;
  unsigned short* outp = out + (size_t)e * R * C;
  int c0 = blockIdx.x * 32, r0 = blockIdx.y * 32;
  int tx = threadIdx.x & 31, ty = threadIdx.x >> 5;  // ty 0..7
#pragma unroll
  for (int i = 0; i < 32; i += 8)
    tile[ty + i][tx] = f2bf(inp[(size_t)(r0 + ty + i) * C + (c0 + tx)]);
  __syncthreads();
#pragma unroll
  for (int i = 0; i < 32; i += 8)
    outp[(size_t)(c0 + ty + i) * R + (r0 + tx)] = tile[tx][ty + i];
}

// ---------------- GEMM12: inter = silu(A@wi0) * (A@wi1), bf16 MFMA ----------
// A: sorted_x [CAP][DIM] bf16 row-major; W0t/W1t: [NE][MDIM][DIM] bf16 (N-major, K-contig)
// Dense tile grid: blockIdx.x is a flat 128-row tile index; expert found via tstart[].
__global__ __launch_bounds__(256) void gemm12_kernel(
    const unsigned short* __restrict__ A, const unsigned short* __restrict__ W0t,
    const unsigned short* __restrict__ W1t, const int* __restrict__ offsets,
    const int* __restrict__ tstart, unsigned short* __restrict__ inter) {
  int bx = blockIdx.x;
  if (bx >= tstart[NE]) return;
  int e = 0;
#pragma unroll
  for (int k = 1; k < NE; k++) if (tstart[k] <= bx) e = k;
  int row0 = offsets[e], row_end = offsets[e + 1];
  int tile_r0 = row0 + (bx - tstart[e]) * 128;
  if (tile_r0 >= row_end) return;
  int col0 = blockIdx.y * 64;

  __shared__ unsigned short As[128 * 32];
  __shared__ unsigned short B0s[64 * 32];
  __shared__ unsigned short B1s[64 * 32];

  int tid = threadIdx.x;
  int wave = tid >> 6, lane = tid & 63;
  int wm = wave >> 1, wn = wave & 1;  // wave tile: 64 rows x 32 cols (per matrix)

  const unsigned short* B0 = W0t + ((size_t)e * MDIM + col0) * DIM;
  const unsigned short* B1 = W1t + ((size_t)e * MDIM + col0) * DIM;

  f32x4 acc0[4][2], acc1[4][2];
#pragma unroll
  for (int i = 0; i < 4; i++)
#pragma unroll
    for (int j = 0; j < 2; j++) {
      acc0[i][j] = (f32x4){0.f, 0.f, 0.f, 0.f};
      acc1[i][j] = (f32x4){0.f, 0.f, 0.f, 0.f};
    }

  int lrow = lane >> 2;            // 0..15
  int lkoff = (lane & 3) * 8;      // element offset within 32-wide K chunk

  for (int k0 = 0; k0 < DIM; k0 += 32) {
#pragma unroll
    for (int c = 0; c < 2; c++) {
      int r = wave * 32 + c * 16 + lrow;
      gload_lds16(A + (size_t)(tile_r0 + r) * DIM + k0 + lkoff,
                  &As[(wave * 32 + c * 16) * 32]);
    }
    {
      int r = wave * 16 + lrow;
      gload_lds16(B0 + (size_t)r * DIM + k0 + lkoff, &B0s[(wave * 16) * 32]);
      gload_lds16(B1 + (size_t)r * DIM + k0 + lkoff, &B1s[(wave * 16) * 32]);
    }
    __syncthreads();
    bf16x8 af[4], b0f[2], b1f[2];
#pragma unroll
    for (int mi = 0; mi < 4; mi++)
      af[mi] = *(const bf16x8*)&As[(wm * 64 + mi * 16 + (lane & 15)) * 32 + (lane >> 4) * 8];
#pragma unroll
    for (int ni = 0; ni < 2; ni++) {
      b0f[ni] = *(const bf16x8*)&B0s[(wn * 32 + ni * 16 + (lane & 15)) * 32 + (lane >> 4) * 8];
      b1f[ni] = *(const bf16x8*)&B1s[(wn * 32 + ni * 16 + (lane & 15)) * 32 + (lane >> 4) * 8];
    }
#pragma unroll
    for (int mi = 0; mi < 4; mi++)
#pragma unroll
      for (int ni = 0; ni < 2; ni++) {
        acc0[mi][ni] = __builtin_amdgcn_mfma_f32_16x16x32_bf16(af[mi], b0f[ni], acc0[mi][ni], 0, 0, 0);
        acc1[mi][ni] = __builtin_amdgcn_mfma_f32_16x16x32_bf16(af[mi], b1f[ni], acc1[mi][ni], 0, 0, 0);
      }
    __syncthreads();
  }
  // epilogue: silu(h0)*h1 -> inter (bf16). C/D: col=lane&15, row=(lane>>4)*4+reg
#pragma unroll
  for (int mi = 0; mi < 4; mi++)
#pragma unroll
    for (int reg = 0; reg < 4; reg++) {
      int grow = tile_r0 + wm * 64 + mi * 16 + (lane >> 4) * 4 + reg;
      if (grow < row_end) {
#pragma unroll
        for (int ni = 0; ni < 2; ni++) {
          float h0 = acc0[mi][ni][reg];
          float h1 = acc1[mi][ni][reg];
          float g = h0 / (1.0f + __expf(-h0));
          int col = col0 + wn * 32 + ni * 16 + (lane & 15);
          inter[(size_t)grow * MDIM + col] = f2bf(g * h1);
        }
      }
    }
}

// ---------------- GEMM3: out_sorted = inter @ wo  (plain f32 stores) --------
// A: inter [CAP][MDIM] bf16; Wot: [NE][DIM][MDIM] bf16 (N-major, K-contig)
__global__ __launch_bounds__(256) void gemm3_kernel(
    const unsigned short* __restrict__ A, const unsigned short* __restrict__ Wot,
    const int* __restrict__ offsets, const int* __restrict__ tstart,
    float* __restrict__ out_sorted) {
  int bx = blockIdx.x;
  if (bx >= tstart[NE]) return;
  int e = 0;
#pragma unroll
  for (int k = 1; k < NE; k++) if (tstart[k] <= bx) e = k;
  int row0 = offsets[e], row_end = offsets[e + 1];
  int tile_r0 = row0 + (bx - tstart[e]) * 128;
  if (tile_r0 >= row_end) return;
  int col0 = blockIdx.y * 128;

  __shared__ unsigned short As[128 * 32];
  __shared__ unsigned short Bs[128 * 32];

  int tid = threadIdx.x;
  int wave = tid >> 6, lane = tid & 63;
  int wm = wave >> 1, wn = wave & 1;  // wave tile: 64 x 64

  const unsigned short* B = Wot + ((size_t)e * DIM + col0) * MDIM;

  f32x4 acc[4][4];
#pragma unroll
  for (int i = 0; i < 4; i++)
#pragma unroll
    for (int j = 0; j < 4; j++) acc[i][j] = (f32x4){0.f, 0.f, 0.f, 0.f};

  int lrow = lane >> 2;
  int lkoff = (lane & 3) * 8;

  for (int k0 = 0; k0 < MDIM; k0 += 32) {
#pragma unroll
    for (int c = 0; c < 2; c++) {
      int r = wave * 32 + c * 16 + lrow;
      gload_lds16(A + (size_t)(tile_r0 + r) * MDIM + k0 + lkoff,
                  &As[(wave * 32 + c * 16) * 32]);
      gload_lds16(B + (size_t)r * MDIM + k0 + lkoff,
                  &Bs[(wave * 32 + c * 16) * 32]);
    }
    __syncthreads();
    bf16x8 af[4], bfr[4];
#pragma unroll
    for (int mi = 0; mi < 4; mi++)
      af[mi] = *(const bf16x8*)&As[(wm * 64 + mi * 16 + (lane & 15)) * 32 + (lane >> 4) * 8];
#pragma unroll
    for (int ni = 0; ni < 4; ni++)
      bfr[ni] = *(const bf16x8*)&Bs[(wn * 64 + ni * 16 + (lane & 15)) * 32 + (lane >> 4) * 8];
#pragma unroll
    for (int mi = 0; mi < 4; mi++)
#pragma unroll
      for (int ni = 0; ni < 4; ni++)
        acc[mi][ni] = __builtin_amdgcn_mfma_f32_16x16x32_bf16(af[mi], bfr[ni], acc[mi][ni], 0, 0, 0);
    __syncthreads();
  }
  // epilogue: plain f32 stores (no atomics)
#pragma unroll
  for (int mi = 0; mi < 4; mi++)
#pragma unroll
    for (int reg = 0; reg < 4; reg++) {
      int grow = tile_r0 + wm * 64 + mi * 16 + (lane >> 4) * 4 + reg;
      if (grow < row_end) {
        float* orow = out_sorted + (size_t)grow * DIM + col0 + wn * 64 + (lane & 15);
#pragma unroll
        for (int ni = 0; ni < 4; ni++)
          orow[ni * 16] = acc[mi][ni][reg];
      }
    }
}

// ---------------- combine: out[t] = w0*os[slot0] + w1*os[slot1] -------------
__global__ __launch_bounds__(256) void combine_kernel(
    const float* __restrict__ os, const int* __restrict__ tok_slot,
    const float* __restrict__ tok_w, float* __restrict__ out) {
  int t = blockIdx.x * 4 + (threadIdx.x >> 6);
  int lane = threadIdx.x & 63;
  int s0 = tok_slot[2 * t], s1 = tok_slot[2 * t + 1];
  float w0 = tok_w[2 * t], w1 = tok_w[2 * t + 1];
  const float4* a = (const float4*)(os + (size_t)s0 * DIM);
  const float4* b = (const float4*)(os + (size_t)s1 * DIM);
  float4* o = (float4*)(out + (size_t)t * DIM);
#pragma unroll
  for (int i = lane; i < DIM / 4; i += 64) {
    float4 va = a[i], vb = b[i];
    float4 r;
    r.x = w0 * va.x + w1 * vb.x;
    r.y = w0 * va.y + w1 * vb.y;
    r.z = w0 * va.z + w1 * vb.z;
    r.w = w0 * va.w + w1 * vb.w;
    o[i] = r;
  }
}

// ---------------------------------------------------------------------------
extern "C" void kernel_launch(void* const* d_in, const int* in_sizes, int n_in,
                              void* d_out, int out_size, void* d_ws, size_t ws_size,
                              hipStream_t stream) {
  const float* x   = (const float*)d_in[0];
  const float* wg  = (const float*)d_in[1];
  const float* wi0 = (const float*)d_in[2];
  const float* wi1 = (const float*)d_in[3];
  const float* wo  = (const float*)d_in[4];
  float* out = (float*)d_out;

  char* ws = (char*)d_ws;
  size_t off = 0;
  auto alloc = [&](size_t bytes) -> void* {
    void* p = ws + off;
    off = (off + bytes + 255) & ~(size_t)255;
    return p;
  };
  int*   offsets  = (int*)alloc((NE + 1) * 4);
  int*   tstart   = (int*)alloc((NE + 1) * 4);
  int*   tok_eid  = (int*)alloc((size_t)2 * T_TOK * 4);
  float* tok_w    = (float*)alloc((size_t)2 * T_TOK * 4);
  int*   tok_slot = (int*)alloc((size_t)2 * T_TOK * 4);
  unsigned short* inter    = (unsigned short*)alloc((size_t)CAP * MDIM * 2);
  // sorted_x + W0t + W1t form one contiguous 134.77 MB window; after gemm12
  // they are dead and out_sorted (16384*DIM*4 = 134.22 MB) aliases the window.
  unsigned short* sorted_x = (unsigned short*)alloc((size_t)CAP * DIM * 2);
  unsigned short* W0t      = (unsigned short*)alloc((size_t)NE * MDIM * DIM * 2);
  unsigned short* W1t      = (unsigned short*)alloc((size_t)NE * MDIM * DIM * 2);
  unsigned short* Wot      = (unsigned short*)alloc((size_t)NE * DIM * MDIM * 2);
  float* out_sorted = (float*)sorted_x;  // alias (see above)

  router_kernel<<<T_TOK / 16, 256, 0, stream>>>(x, wg, tok_eid, tok_w);
  plan_kernel<<<1, 256, 0, stream>>>(tok_eid, offsets, tstart, tok_slot);
  dispatch_kernel<<<T_TOK, 256, 0, stream>>>(x, tok_slot, sorted_x);
  // wi_0 [E][D][M] -> W0t [E][M][D]; wi_1 likewise; wo [E][M][D] -> Wot [E][D][M]
  transpose_cast_kernel<<<dim3(MDIM / 32, DIM / 32, NE), 256, 0, stream>>>(wi0, W0t, DIM, MDIM);
  transpose_cast_kernel<<<dim3(MDIM / 32, DIM / 32, NE), 256, 0, stream>>>(wi1, W1t, DIM, MDIM);
  transpose_cast_kernel<<<dim3(DIM / 32, MDIM / 32, NE), 256, 0, stream>>>(wo, Wot, MDIM, DIM);

  gemm12_kernel<<<dim3(MAXTILES, MDIM / 64, 1), 256, 0, stream>>>(
      sorted_x, W0t, W1t, offsets, tstart, inter);
  gemm3_kernel<<<dim3(MAXTILES, DIM / 128, 1), 256, 0, stream>>>(
      inter, Wot, offsets, tstart, out_sorted);
  combine_kernel<<<T_TOK / 4, 256, 0, stream>>>(out_sorted, tok_slot, tok_w, out);
}